// Round 1
// baseline (37160.901 us; speedup 1.0000x reference)
//
#include <hip/hip_runtime.h>
#include <hip/hip_bf16.h>

// Problem constants (from reference): N=8192, Din=1024, H=1024, 4H=4096.
#define NSTEP 8192
#define DIN   1024
#define HDIM  1024
#define G4    4096   // 4*H

// ---------------------------------------------------------------------------
// Phase A: x_gates[n][m] = dot(xs[n,:], W_ih[m,:]) + b_ih[m] + b_hh[m]
// f32 tiled GEMM (NT form: both operands K-contiguous). 64x64 tile, BK=32,
// 256 threads, 4x4 outputs/thread, transposed LDS tiles for float4 reads.
// ---------------------------------------------------------------------------
__global__ __launch_bounds__(256) void gemm_xgates(
    const float* __restrict__ xs,    // [8192,1024]
    const float* __restrict__ Wih,   // [4096,1024]
    const float* __restrict__ bih,   // [4096]
    const float* __restrict__ bhh,   // [4096]
    float* __restrict__ xg)          // [8192,4096]
{
    __shared__ float a_s[32][68];    // [k][n]  (+4 pad keeps 16B align, spreads banks)
    __shared__ float b_s[32][68];    // [k][m]

    const int bm = blockIdx.x;       // 0..63   (gate-row tiles)
    const int bn = blockIdx.y;       // 0..127  (xs-row tiles)
    const int tid = threadIdx.x;
    const int tx = tid & 15;         // -> m
    const int ty = tid >> 4;         // -> n

    float acc[4][4] = {};

    for (int k0 = 0; k0 < DIN; k0 += 32) {
        // stage 64 rows x 32 k of A and B (coalesced float4 global reads)
        #pragma unroll
        for (int s = tid; s < 512; s += 256) {
            const int r  = s >> 3;
            const int kk = (s & 7) << 2;
            const float4 av = *(const float4*)&xs[(size_t)(bn * 64 + r) * DIN + k0 + kk];
            a_s[kk + 0][r] = av.x; a_s[kk + 1][r] = av.y;
            a_s[kk + 2][r] = av.z; a_s[kk + 3][r] = av.w;
            const float4 bv = *(const float4*)&Wih[(size_t)(bm * 64 + r) * DIN + k0 + kk];
            b_s[kk + 0][r] = bv.x; b_s[kk + 1][r] = bv.y;
            b_s[kk + 2][r] = bv.z; b_s[kk + 3][r] = bv.w;
        }
        __syncthreads();

        #pragma unroll
        for (int k = 0; k < 32; ++k) {
            const float4 a = *(const float4*)&a_s[k][ty << 2];
            const float4 b = *(const float4*)&b_s[k][tx << 2];
            acc[0][0] = fmaf(a.x, b.x, acc[0][0]); acc[0][1] = fmaf(a.x, b.y, acc[0][1]);
            acc[0][2] = fmaf(a.x, b.z, acc[0][2]); acc[0][3] = fmaf(a.x, b.w, acc[0][3]);
            acc[1][0] = fmaf(a.y, b.x, acc[1][0]); acc[1][1] = fmaf(a.y, b.y, acc[1][1]);
            acc[1][2] = fmaf(a.y, b.z, acc[1][2]); acc[1][3] = fmaf(a.y, b.w, acc[1][3]);
            acc[2][0] = fmaf(a.z, b.x, acc[2][0]); acc[2][1] = fmaf(a.z, b.y, acc[2][1]);
            acc[2][2] = fmaf(a.z, b.z, acc[2][2]); acc[2][3] = fmaf(a.z, b.w, acc[2][3]);
            acc[3][0] = fmaf(a.w, b.x, acc[3][0]); acc[3][1] = fmaf(a.w, b.y, acc[3][1]);
            acc[3][2] = fmaf(a.w, b.z, acc[3][2]); acc[3][3] = fmaf(a.w, b.w, acc[3][3]);
        }
        __syncthreads();
    }

    const int m0 = bm * 64 + (tx << 2);
    const float4 bias = make_float4(bih[m0 + 0] + bhh[m0 + 0],
                                    bih[m0 + 1] + bhh[m0 + 1],
                                    bih[m0 + 2] + bhh[m0 + 2],
                                    bih[m0 + 3] + bhh[m0 + 3]);
    #pragma unroll
    for (int u = 0; u < 4; ++u) {
        const int n = bn * 64 + (ty << 2) + u;
        float4 v = make_float4(acc[u][0] + bias.x, acc[u][1] + bias.y,
                               acc[u][2] + bias.z, acc[u][3] + bias.w);
        *(float4*)&xg[(size_t)n * G4 + m0] = v;
    }
}

// ---------------------------------------------------------------------------
// Phase B: persistent recurrence. 64 WGs x 512 threads (cooperative launch).
// WG w owns h indices [w*16, w*16+16) -> 64 W_hh rows (4 gate blocks x 16),
// held entirely in VGPRs (128 f32/thread). h broadcast via global double
// buffer with AGENT-scope atomics (per-XCD L2 not coherent). One device-scope
// atomic counter implements the per-step grid barrier.
// Thread map: wave wv (0..7): gate q = wv>>1, jloc = (wv&1)*8 + (lane>>3),
// sub = lane&7 covers k = sub*4 + 32*i (+0..3), i=0..31  (bank-conflict-free).
// ---------------------------------------------------------------------------
#define REC_G 64
#define REC_T 512

__global__ __launch_bounds__(REC_T, 2) void lstm_rec(
    const float* __restrict__ xg,    // [NSTEP, 4096]
    const float* __restrict__ Whh,   // [4096, 1024]
    const float* __restrict__ h0,    // [1024]
    const float* __restrict__ c0,    // [1024]
    float* __restrict__ ys,          // [NSTEP, 1024]
    float* hbuf,                     // [2][1024]  (workspace)
    unsigned int* bar)               // workspace, memset to 0 before launch
{
    __shared__ float h_lds[HDIM];
    __shared__ float gacc[4][16];
    __shared__ float c_lds[16];

    const int wg   = blockIdx.x;          // 0..63
    const int tid  = threadIdx.x;
    const int lane = tid & 63;
    const int wv   = tid >> 6;            // 0..7
    const int q    = wv >> 1;             // gate 0..3
    const int jloc = ((wv & 1) << 3) + (lane >> 3);  // 0..15
    const int sub  = lane & 7;
    const int j0   = wg << 4;
    const int row  = q * HDIM + j0 + jloc;   // global gate row

    // Preload owned W_hh strip into registers: wreg[i] = Whh[row][sub*4+32i ..+3]
    float4 wreg[32];
    #pragma unroll
    for (int i = 0; i < 32; ++i)
        wreg[i] = *(const float4*)&Whh[(size_t)row * HDIM + (sub << 2) + (i << 5)];

    // Init carry state (every call: deterministic)
    if (tid < 16) {
        c_lds[tid] = c0[j0 + tid];
        __hip_atomic_store(&hbuf[j0 + tid], h0[j0 + tid],
                           __ATOMIC_RELAXED, __HIP_MEMORY_SCOPE_AGENT);
    }
    __syncthreads();   // drains vmcnt: agent stores complete

    unsigned int target = REC_G;
    if (tid == 0) {
        __hip_atomic_fetch_add(bar, 1u, __ATOMIC_RELEASE, __HIP_MEMORY_SCOPE_AGENT);
        while (__hip_atomic_load(bar, __ATOMIC_ACQUIRE, __HIP_MEMORY_SCOPE_AGENT) < target)
            __builtin_amdgcn_s_sleep(1);
    }
    __syncthreads();

    // Prefetch x_gates for t=0 (held by sub==0 lanes)
    float xg_next = 0.f;
    if (sub == 0) xg_next = xg[row];

    for (int t = 0; t < NSTEP; ++t) {
        const int cur = t & 1;
        const int nxt = cur ^ 1;

        // Broadcast h into LDS (agent loads bypass stale L2)
        #pragma unroll
        for (int k = tid; k < HDIM; k += REC_T)
            h_lds[k] = __hip_atomic_load(&hbuf[cur * HDIM + k],
                                         __ATOMIC_RELAXED, __HIP_MEMORY_SCOPE_AGENT);

        const float xg_cur = xg_next;
        if (sub == 0 && t + 1 < NSTEP)
            xg_next = xg[(size_t)(t + 1) * G4 + row];   // prefetch next step

        __syncthreads();

        // 1024-long dot product, 128 MACs/thread, W in regs, h from LDS
        float acc = 0.f;
        #pragma unroll
        for (int i = 0; i < 32; ++i) {
            const float4 hv = *(const float4*)&h_lds[(sub << 2) + (i << 5)];
            acc = fmaf(wreg[i].x, hv.x, acc);
            acc = fmaf(wreg[i].y, hv.y, acc);
            acc = fmaf(wreg[i].z, hv.z, acc);
            acc = fmaf(wreg[i].w, hv.w, acc);
        }
        // reduce across the 8 k-chunks (sub lanes)
        acc += __shfl_xor(acc, 1);
        acc += __shfl_xor(acc, 2);
        acc += __shfl_xor(acc, 4);
        if (sub == 0) gacc[q][jloc] = acc + xg_cur;
        __syncthreads();

        // Gating + state update (16 owner threads)
        if (tid < 16) {
            const float gi = gacc[0][tid];
            const float gf = gacc[1][tid];
            const float gg = gacc[2][tid];
            const float go = gacc[3][tid];
            const float i_ = 1.f / (1.f + __expf(-gi));
            const float f_ = 1.f / (1.f + __expf(-gf));
            const float g_ = tanhf(gg);
            const float o_ = 1.f / (1.f + __expf(-go));
            const float c_ = f_ * c_lds[tid] + i_ * g_;
            c_lds[tid] = c_;
            const float h_ = o_ * tanhf(c_);
            ys[(size_t)t * HDIM + j0 + tid] = h_;
            __hip_atomic_store(&hbuf[nxt * HDIM + j0 + tid], h_,
                               __ATOMIC_RELAXED, __HIP_MEMORY_SCOPE_AGENT);
        }
        __syncthreads();   // drains vmcnt: h stores complete before arrival

        // Grid barrier (device-scope atomic counter, monotonic)
        target += REC_G;
        if (tid == 0) {
            __hip_atomic_fetch_add(bar, 1u, __ATOMIC_RELEASE, __HIP_MEMORY_SCOPE_AGENT);
            while (__hip_atomic_load(bar, __ATOMIC_ACQUIRE, __HIP_MEMORY_SCOPE_AGENT) < target)
                __builtin_amdgcn_s_sleep(1);
        }
        __syncthreads();
    }
}

// ---------------------------------------------------------------------------
extern "C" void kernel_launch(void* const* d_in, const int* in_sizes, int n_in,
                              void* d_out, int out_size, void* d_ws, size_t ws_size,
                              hipStream_t stream) {
    const float* xs  = (const float*)d_in[0];
    const float* Wih = (const float*)d_in[1];
    const float* Whh = (const float*)d_in[2];
    const float* bih = (const float*)d_in[3];
    const float* bhh = (const float*)d_in[4];
    const float* h0  = (const float*)d_in[5];
    const float* c0  = (const float*)d_in[6];
    float* ys = (float*)d_out;

    // Workspace layout
    const size_t XG_BYTES = (size_t)NSTEP * G4 * sizeof(float);   // 134 MB
    float* xg = (float*)d_ws;
    float* hbuf = (float*)((char*)d_ws + XG_BYTES);
    unsigned int* bar = (unsigned int*)((char*)d_ws + XG_BYTES + 2 * HDIM * sizeof(float));

    // barrier counter must start at 0 every call
    hipMemsetAsync(bar, 0, sizeof(unsigned int), stream);

    // Phase A: input projection GEMM
    dim3 gridA(G4 / 64, NSTEP / 64);
    gemm_xgates<<<gridA, 256, 0, stream>>>(xs, Wih, bih, bhh, xg);

    // Phase B: persistent recurrence (cooperative: all 64 WGs co-resident)
    void* args[] = {(void*)&xg, (void*)&Whh, (void*)&h0, (void*)&c0,
                    (void*)&ys, (void*)&hbuf, (void*)&bar};
    hipLaunchCooperativeKernel((void*)lstm_rec, dim3(REC_G), dim3(REC_T),
                               args, 0, stream);
}